// Round 6
// baseline (122.465 us; speedup 1.0000x reference)
//
#include <hip/hip_runtime.h>

// MLPPredictor: score[e] = concat(nfeats[src[e]], nfeats[dst[e]], efeats[e]) @ W^T + b
// E = 625000, N = 100000, D = 128, OUT = 2.
//
// Two-kernel affine split, BOTH kernels one-item-per-lane (no cross-lane
// reduction, no vmcnt(0) tail -> continuous memory issue):
//   p[n] = (n@W0s, n@W1s, n@W0d, n@W1d)   -> float4 table (1.6 MB, L2-resident)
//   score[e] = efeats[e]@We + p[src].xy + p[dst].zw + b
// W rows staged in LDS, read as uniform-address ds_read_b128 broadcasts.
// Each lane streams its own 512 B row as 8 chunks of 4x f32x4 (the 3 trailing
// loads of a chunk hit the L1 line fetched by the first -> no over-fetch).

static constexpr int D = 128;
static constexpr int THREADS = 256;

typedef float f32x4 __attribute__((ext_vector_type(4)));

// ---------- kernel 1: per-node partials, one node per lane ----------
__global__ __launch_bounds__(THREADS) void node_partial_pl(
    const float* __restrict__ nfeats,   // [N, 128]
    const float* __restrict__ W,        // [2, 384]
    float*       __restrict__ pf,       // [N*4] (s0, s1, d0, d1)
    int N)
{
    __shared__ float ws[512];  // [s0 | s1 | d0 | d1] x 128 floats
    for (int t = threadIdx.x; t < 512; t += THREADS) {
        const int o = t & 127;
        const int r = t >> 7;                      // 0:s0 1:s1 2:d0 3:d1
        const int off = (r & 1) * 384 + (r >> 1) * 128;  // 0,384,128,512
        ws[t] = W[off + o];
    }
    __syncthreads();

    const int n0     = blockIdx.x * THREADS + threadIdx.x;
    const int stride = gridDim.x * THREADS;

    for (int n = n0; n < N; n += stride) {
        const float* row = nfeats + (size_t)n * D;
        float s0 = 0.f, s1 = 0.f, d0 = 0.f, d1 = 0.f;

        #pragma unroll
        for (int c = 0; c < 8; ++c) {
            f32x4 h[4];
            #pragma unroll
            for (int k = 0; k < 4; ++k)
                h[k] = *reinterpret_cast<const f32x4*>(row + 16 * c + 4 * k);
            #pragma unroll
            for (int k = 0; k < 4; ++k) {
                const float4 w0 = *reinterpret_cast<const float4*>(&ws[      16 * c + 4 * k]);
                const float4 w1 = *reinterpret_cast<const float4*>(&ws[128 + 16 * c + 4 * k]);
                const float4 w2 = *reinterpret_cast<const float4*>(&ws[256 + 16 * c + 4 * k]);
                const float4 w3 = *reinterpret_cast<const float4*>(&ws[384 + 16 * c + 4 * k]);
                s0 += h[k].x * w0.x + h[k].y * w0.y + h[k].z * w0.z + h[k].w * w0.w;
                s1 += h[k].x * w1.x + h[k].y * w1.y + h[k].z * w1.z + h[k].w * w1.w;
                d0 += h[k].x * w2.x + h[k].y * w2.y + h[k].z * w2.z + h[k].w * w2.w;
                d1 += h[k].x * w3.x + h[k].y * w3.y + h[k].z * w3.z + h[k].w * w3.w;
            }
        }
        *reinterpret_cast<float4*>(pf + 4 * (size_t)n) = make_float4(s0, s1, d0, d1);
    }
}

// ---------- kernel 2: streamed edge kernel, one edge per lane ----------
__global__ __launch_bounds__(THREADS) void edge_kernel_pl(
    const float* __restrict__ efeats,   // [E, 128]
    const int*   __restrict__ src,      // [E]
    const int*   __restrict__ dst,      // [E]
    const float* __restrict__ W,        // [2, 384]
    const float* __restrict__ bias,     // [2]
    const float* __restrict__ pf,       // [N*4]
    float*       __restrict__ out,      // [E, 2]
    int E)
{
    __shared__ float ws[256];  // [We0 | We1] x 128 floats
    {
        const int t = threadIdx.x;
        ws[t] = (t < 128) ? W[256 + t] : W[640 + (t - 128)];
    }
    __syncthreads();

    const float b0 = bias[0];
    const float b1 = bias[1];

    const int e0     = blockIdx.x * THREADS + threadIdx.x;
    const int stride = gridDim.x * THREADS;

    for (int e = e0; e < E; e += stride) {
        // issue index + table gathers first; latency hides under the row stream
        const int s = src[e];
        const int d = dst[e];
        const float2 ps  = *reinterpret_cast<const float2*>(pf + 4 * (size_t)s);      // s0,s1
        const float2 pdv = *reinterpret_cast<const float2*>(pf + 4 * (size_t)d + 2);  // d0,d1

        const float* row = efeats + (size_t)e * D;
        float a0 = 0.f, a1 = 0.f;

        #pragma unroll
        for (int c = 0; c < 8; ++c) {
            f32x4 h[4];
            #pragma unroll
            for (int k = 0; k < 4; ++k)
                h[k] = *reinterpret_cast<const f32x4*>(row + 16 * c + 4 * k);
            #pragma unroll
            for (int k = 0; k < 4; ++k) {
                const float4 w0 = *reinterpret_cast<const float4*>(&ws[      16 * c + 4 * k]);
                const float4 w1 = *reinterpret_cast<const float4*>(&ws[128 + 16 * c + 4 * k]);
                a0 += h[k].x * w0.x + h[k].y * w0.y + h[k].z * w0.z + h[k].w * w0.w;
                a1 += h[k].x * w1.x + h[k].y * w1.y + h[k].z * w1.z + h[k].w * w1.w;
            }
        }

        *reinterpret_cast<float2*>(out + 2 * (size_t)e) =
            make_float2(a0 + ps.x + pdv.x + b0, a1 + ps.y + pdv.y + b1);
    }
}

// ---------- fallback: single-kernel (if ws too small) ----------
__global__ __launch_bounds__(THREADS) void mlp_pred_fused_kernel(
    const float* __restrict__ nfeats, const float* __restrict__ efeats,
    const int* __restrict__ src, const int* __restrict__ dst,
    const float* __restrict__ W, const float* __restrict__ bias,
    float* __restrict__ out, int E)
{
    const int sl = threadIdx.x & 31;
    const int gib = threadIdx.x >> 5;
    const int g0 = blockIdx.x * (THREADS / 32) + gib;
    const int ngrp = gridDim.x * (THREADS / 32);

    const float4 w0s = *reinterpret_cast<const float4*>(W +   0 + 4 * sl);
    const float4 w0d = *reinterpret_cast<const float4*>(W + 128 + 4 * sl);
    const float4 w0e = *reinterpret_cast<const float4*>(W + 256 + 4 * sl);
    const float4 w1s = *reinterpret_cast<const float4*>(W + 384 +   0 + 4 * sl);
    const float4 w1d = *reinterpret_cast<const float4*>(W + 384 + 128 + 4 * sl);
    const float4 w1e = *reinterpret_cast<const float4*>(W + 384 + 256 + 4 * sl);
    const float b0 = bias[0];
    const float b1 = bias[1];

    for (int e = g0; e < E; e += ngrp) {
        const int si = src[e];
        const int di = dst[e];
        const float4 hs = *reinterpret_cast<const float4*>(nfeats + (size_t)si * D + 4 * sl);
        const float4 hd = *reinterpret_cast<const float4*>(nfeats + (size_t)di * D + 4 * sl);
        const float4 he = *reinterpret_cast<const float4*>(efeats + (size_t)e  * D + 4 * sl);

        float a0 = hs.x * w0s.x + hs.y * w0s.y + hs.z * w0s.z + hs.w * w0s.w;
        a0 += hd.x * w0d.x + hd.y * w0d.y + hd.z * w0d.z + hd.w * w0d.w;
        a0 += he.x * w0e.x + he.y * w0e.y + he.z * w0e.z + he.w * w0e.w;
        float a1 = hs.x * w1s.x + hs.y * w1s.y + hs.z * w1s.z + hs.w * w1s.w;
        a1 += hd.x * w1d.x + hd.y * w1d.y + hd.z * w1d.z + hd.w * w1d.w;
        a1 += he.x * w1e.x + he.y * w1e.y + he.z * w1e.z + he.w * w1e.w;

        #pragma unroll
        for (int off = 16; off; off >>= 1) {
            a0 += __shfl_xor(a0, off);
            a1 += __shfl_xor(a1, off);
        }
        if (sl == 0)
            *reinterpret_cast<float2*>(out + 2 * (size_t)e) = make_float2(a0 + b0, a1 + b1);
    }
}

extern "C" void kernel_launch(void* const* d_in, const int* in_sizes, int n_in,
                              void* d_out, int out_size, void* d_ws, size_t ws_size,
                              hipStream_t stream) {
    const float* nfeats = (const float*)d_in[0];
    const float* efeats = (const float*)d_in[1];
    const int*   src    = (const int*)d_in[2];
    const int*   dst    = (const int*)d_in[3];
    const float* W      = (const float*)d_in[4];
    const float* bias   = (const float*)d_in[5];
    float*       out    = (float*)d_out;

    const int E = in_sizes[2];
    const int N = in_sizes[0] / D;

    const size_t p_bytes = (size_t)N * 4 * sizeof(float);

    if (ws_size >= p_bytes) {
        float* pf = (float*)d_ws;

        const int blocks1 = (N + THREADS - 1) / THREADS;   // 391: one node per lane
        node_partial_pl<<<blocks1, THREADS, 0, stream>>>(nfeats, W, pf, N);

        const int blocks2 = (E + THREADS - 1) / THREADS;   // 2442: one edge per lane
        edge_kernel_pl<<<blocks2, THREADS, 0, stream>>>(efeats, src, dst, W, bias, pf, out, E);
    } else {
        int blocks = (E * 32 / THREADS + 1);
        if (blocks > 2048) blocks = 2048;
        mlp_pred_fused_kernel<<<blocks, THREADS, 0, stream>>>(nfeats, efeats, src, dst, W, bias, out, E);
    }
}

// Round 7
// 71.739 us; speedup vs baseline: 1.7071x; 1.7071x over previous
//
#include <hip/hip_runtime.h>

// MLPPredictor: score[e] = concat(nfeats[src[e]], nfeats[dst[e]], efeats[e]) @ W^T + b
// E = 625000, N = 100000, D = 128, OUT = 2.
//
// Two-kernel affine split:
//   p[n] = (n@W0s, n@W1s, n@W0d, n@W1d)  -> float4 table (1.6 MB, L2-resident)
//   score[e] = efeats[e]@We + p[src].xy + p[dst].zw + b
//
// Edge kernel: 8 edges / 32-lane group / iteration, fold-reduction (16 chains
// reduced with 16 shuffles), SOFTWARE-PIPELINED: after the FMA phase consumes
// he[] into v[], the next batch's loads are re-issued into the SAME he[]
// registers, and next-iteration src/dst indices are prefetched. The fold +
// writer-gather + store then run with ~10 loads in flight (no vmcnt(0) tail).

static constexpr int D = 128;
static constexpr int THREADS = 256;
static constexpr int GPB = THREADS / 32;  // 32-lane groups per block

typedef float f32x4 __attribute__((ext_vector_type(4)));

// ---------- kernel 1: per-node partial dot products (2 nodes/group, fold) ----------
__global__ __launch_bounds__(THREADS) void node_partial_kernel(
    const float* __restrict__ nfeats,   // [N, 128]
    const float* __restrict__ W,        // [2, 384]
    float*       __restrict__ pf,       // [N*4] (s0, s1, d0, d1) per node
    int N)
{
    const int sl   = threadIdx.x & 31;
    const int gib  = threadIdx.x >> 5;
    const int g0   = blockIdx.x * GPB + gib;
    const int ngrp = gridDim.x * GPB;

    const float4 w0s = *reinterpret_cast<const float4*>(W +   0 + 4 * sl);
    const float4 w1s = *reinterpret_cast<const float4*>(W + 384 + 4 * sl);
    const float4 w0d = *reinterpret_cast<const float4*>(W + 128 + 4 * sl);
    const float4 w1d = *reinterpret_cast<const float4*>(W + 384 + 128 + 4 * sl);

    for (int n = g0 * 2; n + 1 < N; n += ngrp * 2) {
        float v[8];
        #pragma unroll
        for (int j = 0; j < 2; ++j) {
            const f32x4 h = __builtin_nontemporal_load(
                reinterpret_cast<const f32x4*>(nfeats + (size_t)(n + j) * D + 4 * sl));
            v[j*4+0] = h.x * w0s.x + h.y * w0s.y + h.z * w0s.z + h.w * w0s.w;
            v[j*4+1] = h.x * w1s.x + h.y * w1s.y + h.z * w1s.z + h.w * w1s.w;
            v[j*4+2] = h.x * w0d.x + h.y * w0d.y + h.z * w0d.z + h.w * w0d.w;
            v[j*4+3] = h.x * w1d.x + h.y * w1d.y + h.z * w1d.z + h.w * w1d.w;
        }
        float a4[4];
        #pragma unroll
        for (int c = 0; c < 4; ++c) {
            float send = (sl & 16) ? v[c] : v[c+4];
            float keep = (sl & 16) ? v[c+4] : v[c];
            a4[c] = keep + __shfl_xor(send, 16);
        }
        float a2[2];
        #pragma unroll
        for (int c = 0; c < 2; ++c) {
            float send = (sl & 8) ? a4[c] : a4[c+2];
            float keep = (sl & 8) ? a4[c+2] : a4[c];
            a2[c] = keep + __shfl_xor(send, 8);
        }
        float y;
        {
            float send = (sl & 4) ? a2[0] : a2[1];
            float keep = (sl & 4) ? a2[1] : a2[0];
            y = keep + __shfl_xor(send, 4);
        }
        y += __shfl_xor(y, 2);
        y += __shfl_xor(y, 1);
        if ((sl & 3) == 0) {
            pf[4 * (size_t)n + (sl >> 2)] = y;   // 8 consecutive floats = 32 B
        }
    }
}

// ---------- kernel 2: pipelined streamed edge kernel (8 edges/group) ----------
__global__ __launch_bounds__(THREADS) void edge_kernel(
    const float*  __restrict__ efeats,  // [E, 128]
    const int*    __restrict__ src,     // [E]
    const int*    __restrict__ dst,     // [E]
    const float*  __restrict__ W,       // [2, 384]
    const float*  __restrict__ bias,    // [2]
    const float*  __restrict__ pf,      // [N*4]
    float*        __restrict__ out,     // [E, 2]
    int E)
{
    const int sl   = threadIdx.x & 31;
    const int gib  = threadIdx.x >> 5;
    const int g0   = blockIdx.x * GPB + gib;
    const int ngrp = gridDim.x * GPB;
    const int step = ngrp * 8;

    const float4 w0e = *reinterpret_cast<const float4*>(W + 256 + 4 * sl);
    const float4 w1e = *reinterpret_cast<const float4*>(W + 384 + 256 + 4 * sl);

    const bool wr   = (sl & 1) == 0;
    const int  myj  = sl >> 2;          // writer's edge within the 8-batch
    const int  myo  = (sl >> 1) & 1;    // writer's output index
    const float myb = myo ? bias[1] : bias[0];

    int e = g0 * 8;
    if (e + 7 >= E) return;

    // ---- prologue: issue first batch's loads ----
    f32x4 he[8];
    #pragma unroll
    for (int j = 0; j < 8; ++j)
        he[j] = __builtin_nontemporal_load(
            reinterpret_cast<const f32x4*>(efeats + (size_t)(e + j) * D + 4 * sl));
    int sidx = 0, didx = 0;
    if (wr) {
        sidx = src[e + myj];
        didx = dst[e + myj];
    }

    while (e + 7 < E) {
        const int  en   = e + step;
        const bool more = (en + 7 < E);

        // issue pf gathers for the CURRENT batch (idx prefetched last iter;
        // result needed only at the store, ~fold-latency away)
        float ps = 0.f, pd = 0.f;
        if (wr) {
            ps = pf[(size_t)sidx * 4 + myo];
            pd = pf[(size_t)didx * 4 + 2 + myo];
        }

        // FMA phase consumes he[] -> v[] (waits on the loads issued one
        // iteration ago; they've had a full iteration of latency hiding)
        float v[16];
        #pragma unroll
        for (int j = 0; j < 8; ++j) {
            v[2*j]   = he[j].x * w0e.x + he[j].y * w0e.y + he[j].z * w0e.z + he[j].w * w0e.w;
            v[2*j+1] = he[j].x * w1e.x + he[j].y * w1e.y + he[j].z * w1e.z + he[j].w * w1e.w;
        }

        // re-issue next batch into the SAME registers (he dead after FMA):
        // the fold below runs with these 8+2 loads in flight.
        if (more) {
            #pragma unroll
            for (int j = 0; j < 8; ++j)
                he[j] = __builtin_nontemporal_load(
                    reinterpret_cast<const f32x4*>(efeats + (size_t)(en + j) * D + 4 * sl));
            if (wr) {
                sidx = src[en + myj];
                didx = dst[en + myj];
            }
        }

        // fold 16 -> 8 -> 4 -> 2 -> 1 (masks 16,8,4,2), then butterfly mask 1
        float a8[8];
        #pragma unroll
        for (int c = 0; c < 8; ++c) {
            float send = (sl & 16) ? v[c] : v[c+8];
            float keep = (sl & 16) ? v[c+8] : v[c];
            a8[c] = keep + __shfl_xor(send, 16);
        }
        float a4[4];
        #pragma unroll
        for (int c = 0; c < 4; ++c) {
            float send = (sl & 8) ? a8[c] : a8[c+4];
            float keep = (sl & 8) ? a8[c+4] : a8[c];
            a4[c] = keep + __shfl_xor(send, 8);
        }
        float a2[2];
        #pragma unroll
        for (int c = 0; c < 2; ++c) {
            float send = (sl & 4) ? a4[c] : a4[c+2];
            float keep = (sl & 4) ? a4[c+2] : a4[c];
            a2[c] = keep + __shfl_xor(send, 4);
        }
        float y;
        {
            float send = (sl & 2) ? a2[0] : a2[1];
            float keep = (sl & 2) ? a2[1] : a2[0];
            y = keep + __shfl_xor(send, 2);
        }
        y += __shfl_xor(y, 1);

        // even lane sl holds chain c = sl>>1; 64 B coalesced store per group
        if (wr) {
            out[2 * (size_t)e + (sl >> 1)] = y + ps + pd + myb;
        }

        e = en;
    }
}

// ---------- fallback: single-kernel (if ws too small) ----------
__global__ __launch_bounds__(THREADS) void mlp_pred_fused_kernel(
    const float* __restrict__ nfeats, const float* __restrict__ efeats,
    const int* __restrict__ src, const int* __restrict__ dst,
    const float* __restrict__ W, const float* __restrict__ bias,
    float* __restrict__ out, int E)
{
    const int sl = threadIdx.x & 31;
    const int gib = threadIdx.x >> 5;
    const int g0 = blockIdx.x * GPB + gib;
    const int ngrp = gridDim.x * GPB;

    const float4 w0s = *reinterpret_cast<const float4*>(W +   0 + 4 * sl);
    const float4 w0d = *reinterpret_cast<const float4*>(W + 128 + 4 * sl);
    const float4 w0e = *reinterpret_cast<const float4*>(W + 256 + 4 * sl);
    const float4 w1s = *reinterpret_cast<const float4*>(W + 384 +   0 + 4 * sl);
    const float4 w1d = *reinterpret_cast<const float4*>(W + 384 + 128 + 4 * sl);
    const float4 w1e = *reinterpret_cast<const float4*>(W + 384 + 256 + 4 * sl);
    const float b0 = bias[0];
    const float b1 = bias[1];

    for (int e = g0; e < E; e += ngrp) {
        const int si = src[e];
        const int di = dst[e];
        const float4 hs = *reinterpret_cast<const float4*>(nfeats + (size_t)si * D + 4 * sl);
        const float4 hd = *reinterpret_cast<const float4*>(nfeats + (size_t)di * D + 4 * sl);
        const float4 he = *reinterpret_cast<const float4*>(efeats + (size_t)e  * D + 4 * sl);

        float a0 = hs.x * w0s.x + hs.y * w0s.y + hs.z * w0s.z + hs.w * w0s.w;
        a0 += hd.x * w0d.x + hd.y * w0d.y + hd.z * w0d.z + hd.w * w0d.w;
        a0 += he.x * w0e.x + he.y * w0e.y + he.z * w0e.z + he.w * w0e.w;
        float a1 = hs.x * w1s.x + hs.y * w1s.y + hs.z * w1s.z + hs.w * w1s.w;
        a1 += hd.x * w1d.x + hd.y * w1d.y + hd.z * w1d.z + hd.w * w1d.w;
        a1 += he.x * w1e.x + he.y * w1e.y + he.z * w1e.z + he.w * w1e.w;

        #pragma unroll
        for (int off = 16; off; off >>= 1) {
            a0 += __shfl_xor(a0, off);
            a1 += __shfl_xor(a1, off);
        }
        if (sl == 0)
            *reinterpret_cast<float2*>(out + 2 * (size_t)e) = make_float2(a0 + b0, a1 + b1);
    }
}

extern "C" void kernel_launch(void* const* d_in, const int* in_sizes, int n_in,
                              void* d_out, int out_size, void* d_ws, size_t ws_size,
                              hipStream_t stream) {
    const float* nfeats = (const float*)d_in[0];
    const float* efeats = (const float*)d_in[1];
    const int*   src    = (const int*)d_in[2];
    const int*   dst    = (const int*)d_in[3];
    const float* W      = (const float*)d_in[4];
    const float* bias   = (const float*)d_in[5];
    float*       out    = (float*)d_out;

    const int E = in_sizes[2];
    const int N = in_sizes[0] / D;

    const size_t p_bytes = (size_t)N * 4 * sizeof(float);

    if (ws_size >= p_bytes && (E & 7) == 0 && (N & 1) == 0) {
        float* pf = (float*)d_ws;

        int groups1 = N / 2;
        int blocks1 = (groups1 + GPB - 1) / GPB;
        if (blocks1 > 2048) blocks1 = 2048;
        node_partial_kernel<<<blocks1, THREADS, 0, stream>>>(nfeats, W, pf, N);

        int groups2 = E / 8;
        int blocks2 = (groups2 + GPB - 1) / GPB;
        if (blocks2 > 2048) blocks2 = 2048;
        edge_kernel<<<blocks2, THREADS, 0, stream>>>(efeats, src, dst, W, bias, pf, out, E);
    } else {
        int blocks = (E + GPB - 1) / GPB;
        if (blocks > 2048) blocks = 2048;
        mlp_pred_fused_kernel<<<blocks, THREADS, 0, stream>>>(nfeats, efeats, src, dst, W, bias, out, E);
    }
}

// Round 8
// 70.662 us; speedup vs baseline: 1.7331x; 1.0152x over previous
//
#include <hip/hip_runtime.h>

// MLPPredictor: score[e] = concat(nfeats[src[e]], nfeats[dst[e]], efeats[e]) @ W^T + b
// E = 625000, N = 100000, D = 128, OUT = 2.
//
// Two-kernel affine split:
//   p[n] = (n@W0s, n@W1s, n@W0d, n@W1d)  -> float4 table (1.6 MB, L2-resident)
//   score[e] = efeats[e]@We + p[src].xy + p[dst].zw + b
//
// Edge kernel: 8 edges / 32-lane group / iteration, fold-reduction (16 chains,
// 16 shuffles), DISTANCE-2 software pipeline: two register batches heA/heB,
// loop unrolled x2 (static register assignment); each batch's row loads and
// src/dst indices are issued two batch-processings (~1000 cyc) before use,
// covering full HBM latency (~900 cyc). pf gathers issue at the top of each
// batch processing, consumed after the fold.

static constexpr int D = 128;
static constexpr int THREADS = 256;
static constexpr int GPB = THREADS / 32;  // 32-lane groups per block

typedef float f32x4 __attribute__((ext_vector_type(4)));

__device__ __forceinline__ void load_batch(f32x4 (&he)[8], const float* __restrict__ efeats,
                                           int e, int sl) {
    #pragma unroll
    for (int j = 0; j < 8; ++j)
        he[j] = __builtin_nontemporal_load(
            reinterpret_cast<const f32x4*>(efeats + (size_t)(e + j) * D + 4 * sl));
}

__device__ __forceinline__ void fma_batch(float (&v)[16], const f32x4 (&he)[8],
                                          const float4& w0e, const float4& w1e) {
    #pragma unroll
    for (int j = 0; j < 8; ++j) {
        v[2*j]   = he[j].x * w0e.x + he[j].y * w0e.y + he[j].z * w0e.z + he[j].w * w0e.w;
        v[2*j+1] = he[j].x * w1e.x + he[j].y * w1e.y + he[j].z * w1e.z + he[j].w * w1e.w;
    }
}

__device__ __forceinline__ void fold_store(const float (&v)[16], int sl, bool wr,
                                           float ps, float pd, float myb,
                                           float* __restrict__ out, int e) {
    // fold 16 -> 8 -> 4 -> 2 -> 1 (masks 16,8,4,2), then butterfly mask 1
    float a8[8];
    #pragma unroll
    for (int c = 0; c < 8; ++c) {
        float send = (sl & 16) ? v[c] : v[c+8];
        float keep = (sl & 16) ? v[c+8] : v[c];
        a8[c] = keep + __shfl_xor(send, 16);
    }
    float a4[4];
    #pragma unroll
    for (int c = 0; c < 4; ++c) {
        float send = (sl & 8) ? a8[c] : a8[c+4];
        float keep = (sl & 8) ? a8[c+4] : a8[c];
        a4[c] = keep + __shfl_xor(send, 8);
    }
    float a2[2];
    #pragma unroll
    for (int c = 0; c < 2; ++c) {
        float send = (sl & 4) ? a4[c] : a4[c+2];
        float keep = (sl & 4) ? a4[c+2] : a4[c];
        a2[c] = keep + __shfl_xor(send, 4);
    }
    float y;
    {
        float send = (sl & 2) ? a2[0] : a2[1];
        float keep = (sl & 2) ? a2[1] : a2[0];
        y = keep + __shfl_xor(send, 2);
    }
    y += __shfl_xor(y, 1);

    // even lane sl holds chain c = sl>>1; 64 B coalesced nt store per group
    if (wr) {
        __builtin_nontemporal_store(y + ps + pd + myb, out + 2 * (size_t)e + (sl >> 1));
    }
}

// ---------- kernel 1: per-node partials (2 nodes/group, fold, dist-1 pipeline) ----------
__global__ __launch_bounds__(THREADS) void node_partial_kernel(
    const float* __restrict__ nfeats,   // [N, 128]
    const float* __restrict__ W,        // [2, 384]
    float*       __restrict__ pf,       // [N*4] (s0, s1, d0, d1) per node
    int N)
{
    const int sl   = threadIdx.x & 31;
    const int gib  = threadIdx.x >> 5;
    const int g0   = blockIdx.x * GPB + gib;
    const int ngrp = gridDim.x * GPB;
    const int nstep = ngrp * 2;

    const float4 w0s = *reinterpret_cast<const float4*>(W +   0 + 4 * sl);
    const float4 w1s = *reinterpret_cast<const float4*>(W + 384 + 4 * sl);
    const float4 w0d = *reinterpret_cast<const float4*>(W + 128 + 4 * sl);
    const float4 w1d = *reinterpret_cast<const float4*>(W + 384 + 128 + 4 * sl);

    int n = g0 * 2;
    if (n + 1 >= N) return;

    f32x4 h[2];
    #pragma unroll
    for (int j = 0; j < 2; ++j)
        h[j] = __builtin_nontemporal_load(
            reinterpret_cast<const f32x4*>(nfeats + (size_t)(n + j) * D + 4 * sl));

    while (n + 1 < N) {
        float v[8];
        #pragma unroll
        for (int j = 0; j < 2; ++j) {
            v[j*4+0] = h[j].x * w0s.x + h[j].y * w0s.y + h[j].z * w0s.z + h[j].w * w0s.w;
            v[j*4+1] = h[j].x * w1s.x + h[j].y * w1s.y + h[j].z * w1s.z + h[j].w * w1s.w;
            v[j*4+2] = h[j].x * w0d.x + h[j].y * w0d.y + h[j].z * w0d.z + h[j].w * w0d.w;
            v[j*4+3] = h[j].x * w1d.x + h[j].y * w1d.y + h[j].z * w1d.z + h[j].w * w1d.w;
        }

        const int nn = n + nstep;
        if (nn + 1 < N) {
            #pragma unroll
            for (int j = 0; j < 2; ++j)
                h[j] = __builtin_nontemporal_load(
                    reinterpret_cast<const f32x4*>(nfeats + (size_t)(nn + j) * D + 4 * sl));
        }

        float a4[4];
        #pragma unroll
        for (int c = 0; c < 4; ++c) {
            float send = (sl & 16) ? v[c] : v[c+4];
            float keep = (sl & 16) ? v[c+4] : v[c];
            a4[c] = keep + __shfl_xor(send, 16);
        }
        float a2[2];
        #pragma unroll
        for (int c = 0; c < 2; ++c) {
            float send = (sl & 8) ? a4[c] : a4[c+2];
            float keep = (sl & 8) ? a4[c+2] : a4[c];
            a2[c] = keep + __shfl_xor(send, 8);
        }
        float y;
        {
            float send = (sl & 4) ? a2[0] : a2[1];
            float keep = (sl & 4) ? a2[1] : a2[0];
            y = keep + __shfl_xor(send, 4);
        }
        y += __shfl_xor(y, 2);
        y += __shfl_xor(y, 1);
        if ((sl & 3) == 0) {
            pf[4 * (size_t)n + (sl >> 2)] = y;   // 8 consecutive floats = 32 B
        }
        n = nn;
    }
}

// ---------- kernel 2: distance-2 pipelined edge kernel (8 edges/group) ----------
__global__ __launch_bounds__(THREADS) void edge_kernel(
    const float*  __restrict__ efeats,  // [E, 128]
    const int*    __restrict__ src,     // [E]
    const int*    __restrict__ dst,     // [E]
    const float*  __restrict__ W,       // [2, 384]
    const float*  __restrict__ bias,    // [2]
    const float*  __restrict__ pf,      // [N*4]
    float*        __restrict__ out,     // [E, 2]
    int E)
{
    const int sl   = threadIdx.x & 31;
    const int gib  = threadIdx.x >> 5;
    const int g0   = blockIdx.x * GPB + gib;
    const int ngrp = gridDim.x * GPB;
    const int step = ngrp * 8;

    const float4 w0e = *reinterpret_cast<const float4*>(W + 256 + 4 * sl);
    const float4 w1e = *reinterpret_cast<const float4*>(W + 384 + 256 + 4 * sl);

    const bool wr   = (sl & 1) == 0;
    const int  myj  = sl >> 2;          // writer's edge within the 8-batch
    const int  myo  = (sl >> 1) & 1;    // writer's output index
    const float myb = myo ? bias[1] : bias[0];

    int e = g0 * 8;
    if (e + 7 >= E) return;

    // ---- prologue: fill both pipeline stages ----
    f32x4 heA[8], heB[8];
    int sA = 0, dA = 0, sB = 0, dB = 0;

    load_batch(heA, efeats, e, sl);
    if (wr) { sA = src[e + myj]; dA = dst[e + myj]; }
    if (e + step + 7 < E) {
        load_batch(heB, efeats, e + step, sl);
        if (wr) { sB = src[e + step + myj]; dB = dst[e + step + myj]; }
    }

    for (;;) {
        // ---- process batch in A registers (edges e..e+7) ----
        {
            float ps = 0.f, pd = 0.f;
            if (wr) {
                ps = pf[(size_t)sA * 4 + myo];
                pd = pf[(size_t)dA * 4 + 2 + myo];
            }
            float v[16];
            fma_batch(v, heA, w0e, w1e);
            const int ep = e + 2 * step;          // refill A two stages ahead
            if (ep + 7 < E) {
                load_batch(heA, efeats, ep, sl);
                if (wr) { sA = src[ep + myj]; dA = dst[ep + myj]; }
            }
            fold_store(v, sl, wr, ps, pd, myb, out, e);
        }
        e += step;
        if (e + 7 >= E) break;

        // ---- process batch in B registers (edges e..e+7) ----
        {
            float ps = 0.f, pd = 0.f;
            if (wr) {
                ps = pf[(size_t)sB * 4 + myo];
                pd = pf[(size_t)dB * 4 + 2 + myo];
            }
            float v[16];
            fma_batch(v, heB, w0e, w1e);
            const int ep = e + 2 * step;          // refill B two stages ahead
            if (ep + 7 < E) {
                load_batch(heB, efeats, ep, sl);
                if (wr) { sB = src[ep + myj]; dB = dst[ep + myj]; }
            }
            fold_store(v, sl, wr, ps, pd, myb, out, e);
        }
        e += step;
        if (e + 7 >= E) break;
    }
}

// ---------- fallback: single-kernel (if ws too small) ----------
__global__ __launch_bounds__(THREADS) void mlp_pred_fused_kernel(
    const float* __restrict__ nfeats, const float* __restrict__ efeats,
    const int* __restrict__ src, const int* __restrict__ dst,
    const float* __restrict__ W, const float* __restrict__ bias,
    float* __restrict__ out, int E)
{
    const int sl = threadIdx.x & 31;
    const int gib = threadIdx.x >> 5;
    const int g0 = blockIdx.x * GPB + gib;
    const int ngrp = gridDim.x * GPB;

    const float4 w0s = *reinterpret_cast<const float4*>(W +   0 + 4 * sl);
    const float4 w0d = *reinterpret_cast<const float4*>(W + 128 + 4 * sl);
    const float4 w0e = *reinterpret_cast<const float4*>(W + 256 + 4 * sl);
    const float4 w1s = *reinterpret_cast<const float4*>(W + 384 +   0 + 4 * sl);
    const float4 w1d = *reinterpret_cast<const float4*>(W + 384 + 128 + 4 * sl);
    const float4 w1e = *reinterpret_cast<const float4*>(W + 384 + 256 + 4 * sl);
    const float b0 = bias[0];
    const float b1 = bias[1];

    for (int e = g0; e < E; e += ngrp) {
        const int si = src[e];
        const int di = dst[e];
        const float4 hs = *reinterpret_cast<const float4*>(nfeats + (size_t)si * D + 4 * sl);
        const float4 hd = *reinterpret_cast<const float4*>(nfeats + (size_t)di * D + 4 * sl);
        const float4 he = *reinterpret_cast<const float4*>(efeats + (size_t)e  * D + 4 * sl);

        float a0 = hs.x * w0s.x + hs.y * w0s.y + hs.z * w0s.z + hs.w * w0s.w;
        a0 += hd.x * w0d.x + hd.y * w0d.y + hd.z * w0d.z + hd.w * w0d.w;
        a0 += he.x * w0e.x + he.y * w0e.y + he.z * w0e.z + he.w * w0e.w;
        float a1 = hs.x * w1s.x + hs.y * w1s.y + hs.z * w1s.z + hs.w * w1s.w;
        a1 += hd.x * w1d.x + hd.y * w1d.y + hd.z * w1d.z + hd.w * w1d.w;
        a1 += he.x * w1e.x + he.y * w1e.y + he.z * w1e.z + he.w * w1e.w;

        #pragma unroll
        for (int off = 16; off; off >>= 1) {
            a0 += __shfl_xor(a0, off);
            a1 += __shfl_xor(a1, off);
        }
        if (sl == 0)
            *reinterpret_cast<float2*>(out + 2 * (size_t)e) = make_float2(a0 + b0, a1 + b1);
    }
}

extern "C" void kernel_launch(void* const* d_in, const int* in_sizes, int n_in,
                              void* d_out, int out_size, void* d_ws, size_t ws_size,
                              hipStream_t stream) {
    const float* nfeats = (const float*)d_in[0];
    const float* efeats = (const float*)d_in[1];
    const int*   src    = (const int*)d_in[2];
    const int*   dst    = (const int*)d_in[3];
    const float* W      = (const float*)d_in[4];
    const float* bias   = (const float*)d_in[5];
    float*       out    = (float*)d_out;

    const int E = in_sizes[2];
    const int N = in_sizes[0] / D;

    const size_t p_bytes = (size_t)N * 4 * sizeof(float);

    if (ws_size >= p_bytes && (E & 7) == 0 && (N & 1) == 0) {
        float* pf = (float*)d_ws;

        int groups1 = N / 2;
        int blocks1 = (groups1 + GPB - 1) / GPB;
        if (blocks1 > 2048) blocks1 = 2048;
        node_partial_kernel<<<blocks1, THREADS, 0, stream>>>(nfeats, W, pf, N);

        int groups2 = E / 8;
        int blocks2 = (groups2 + GPB - 1) / GPB;
        if (blocks2 > 2048) blocks2 = 2048;
        edge_kernel<<<blocks2, THREADS, 0, stream>>>(efeats, src, dst, W, bias, pf, out, E);
    } else {
        int blocks = (E + GPB - 1) / GPB;
        if (blocks > 2048) blocks = 2048;
        mlp_pred_fused_kernel<<<blocks, THREADS, 0, stream>>>(nfeats, efeats, src, dst, W, bias, out, E);
    }
}